// Round 6
// baseline (183.698 us; speedup 1.0000x reference)
//
#include <hip/hip_runtime.h>
#include <hip/hip_bf16.h>
#include <math.h>

#define B 8
#define N 256
#define F 64
#define OUTD 256
typedef unsigned long long u64;
typedef __attribute__((ext_vector_type(8))) short bf16x8;
typedef __attribute__((ext_vector_type(4))) float f32x4;

// split x into hi+lo bf16 parts (truncation; residual <= 2^-16 |x|)
__device__ __forceinline__ void build_frag(const float* v8, bf16x8& h, bf16x8& l) {
#pragma unroll
    for (int j = 0; j < 8; ++j) {
        unsigned u = __float_as_uint(v8[j]);
        unsigned hb = u & 0xffff0000u;
        float r = v8[j] - __uint_as_float(hb);
        h[j] = (short)(hb >> 16);
        l[j] = (short)(__float_as_uint(r) >> 16);
    }
}

// ---------------------------------------------------------------------------
// A: fused pack_rows (bx<64) + prep (bx>=64). grid (64+64, B), 256 thr.
//   pack: rowbits[b,i] bit k = adj[b,i,k]!=0   (wave per row, 4 rows/block)
//   prep: base = Wnf@x ; P = Wnm@relu(base)    (wave per node, 4 nodes/block)
// ---------------------------------------------------------------------------
__global__ __launch_bounds__(256) void prepA_kernel(const int* __restrict__ adj,
                                                    const float* __restrict__ X,
                                                    const float* __restrict__ Wnf,
                                                    const float* __restrict__ Wnm,
                                                    u64* __restrict__ rowbits,
                                                    float* __restrict__ base,
                                                    float* __restrict__ P) {
    int b = blockIdx.y;
    int w = threadIdx.x >> 6;
    int lane = threadIdx.x & 63;
    if (blockIdx.x < 64) {
        int i = blockIdx.x * 4 + w;
#pragma unroll
        for (int wd = 0; wd < 4; ++wd) {
            int v = adj[(long)(b * N + i) * N + wd * 64 + lane];
            u64 bits = __ballot(v != 0);
            if (lane == 0) rowbits[(b * N + i) * 4 + wd] = bits;
        }
    } else {
        int n = (blockIdx.x - 64) * 4 + w;   // [0, 256)
        int bi = b * N + n;
        float x = X[(size_t)bi * F + lane];
        float acc = 0.f;
#pragma unroll
        for (int g = 0; g < F; ++g) acc = fmaf(Wnf[lane * F + g], __shfl(x, g, 64), acc);
        base[(size_t)bi * F + lane] = acc;
        float rs = fmaxf(acc, 0.f);
        float acc2 = 0.f;
#pragma unroll
        for (int g = 0; g < F; ++g) acc2 = fmaf(Wnm[lane * F + g], __shfl(rs, g, 64), acc2);
        P[(size_t)bi * F + lane] = acc2;
    }
}

// ---------------------------------------------------------------------------
// B: fused pack_cols + v2. grid (N, B), 256 thr.
//   wave w ballots colbits word w for node i from rowbits, then accumulates
//   V2 partial over its 64 senders. colbits also written for later kernels.
// ---------------------------------------------------------------------------
__global__ __launch_bounds__(256) void v2B_kernel(const float* __restrict__ base,
                                                  const float* __restrict__ P,
                                                  const u64* __restrict__ rowbits,
                                                  u64* __restrict__ colbits,
                                                  float* __restrict__ V2) {
    int i = blockIdx.x, b = blockIdx.y;
    int t = threadIdx.x, w = t >> 6, f = t & 63;
    int bi = b * N + i;
    int bN = b * N;
    int iw = i >> 6, ib = i & 63;
    __shared__ float red[4][F];
    // colbits word w: bit j = adj[b, 64w+j, i] = rowbits[b,64w+j] bit i
    u64 rv = rowbits[(bN + w * 64 + f) * 4 + iw];
    u64 cw = __ballot((rv >> ib) & 1ull);
    if (f == 0) colbits[bi * 4 + w] = cw;
    u64 both = cw & rowbits[bi * 4 + w];
    const float* Pb = P + (size_t)bN * F;
    float acc = 0.f;
    for (int j = 0; j < 64; ++j) {
        float mk = ((both >> j) & 1ull) ? 1.f : 0.f;
        acc += mk * Pb[(w * 64 + j) * F + f];
    }
    red[w][f] = acc;
    __syncthreads();
    if (t < F) V2[(size_t)bi * F + t] = base[(size_t)bi * F + t] + red[0][t] + red[1][t] + red[2][t] + red[3][t];
}

// ---------------------------------------------------------------------------
// s3: V3[b,i] = base[b,i] + Wnm @ (sum_{k in both(i)} relu(V2[b,k]-P[b,i]))
// matvec split over 4 waves (16 g each)
// ---------------------------------------------------------------------------
__global__ __launch_bounds__(256) void s3_kernel(const float* __restrict__ base,
                                                 const float* __restrict__ P,
                                                 const float* __restrict__ V2g,
                                                 const u64* __restrict__ rowbits,
                                                 const u64* __restrict__ colbits,
                                                 const float* __restrict__ Wnm,
                                                 float* __restrict__ V3) {
    int i = blockIdx.x, b = blockIdx.y;
    int t = threadIdx.x, w = t >> 6, f = t & 63;
    int bi = b * N + i;
    __shared__ float red[4][F];
    u64 both = rowbits[bi * 4 + w] & colbits[bi * 4 + w];
    float pif = P[(size_t)bi * F + f];
    const float* Vb = V2g + (size_t)b * N * F;
    float acc = 0.f;
    for (int j = 0; j < 64; ++j) {
        float mk = ((both >> j) & 1ull) ? 1.f : 0.f;
        acc += mk * fmaxf(Vb[(w * 64 + j) * F + f] - pif, 0.f);
    }
    red[w][f] = acc;
    __syncthreads();
    float u = red[0][f] + red[1][f] + red[2][f] + red[3][f];
    __syncthreads();
    // partial matvec over g in [16w, 16w+16)
    float wv[16];
    const float4* wr = (const float4*)(Wnm + (size_t)f * F + 16 * w);
#pragma unroll
    for (int q = 0; q < 4; ++q) *(float4*)&wv[q * 4] = wr[q];
    float a = 0.f;
#pragma unroll
    for (int q = 0; q < 16; ++q) a = fmaf(wv[q], __shfl(u, 16 * w + q, 64), a);
    red[w][f] = a;
    __syncthreads();
    if (t < F) V3[(size_t)bi * F + t] = base[(size_t)bi * F + t] + red[0][t] + red[1][t] + red[2][t] + red[3][t];
}

// ---------------------------------------------------------------------------
// bigstep via MFMA (hi/lo bf16 3-pass ~ fp32), per-kt LDS phasing (17.4 KB):
//   per receiver i (block), 4 waves each own a 64-wide sender chunk;
//   for kt in 0..3 (16 senders):
//     GEMM1: T3[g][k] = Wnm @ relu(V2[i] - P[k])
//     M2[g][k] = both(k) ? relu(V3[k][g] - T3[g][k]) : 0   (via small LDS tile)
//     GEMM2: T4[f][k] = Wnm @ M2  -> acc2[ft][kt]
//   S4 = sum_k T4 ; V4 = base[i] + S4
//   agg[i][f] = sum_{k in row(i)} relu(V4[f] - T4[f][k])
// ---------------------------------------------------------------------------
__global__ __launch_bounds__(256, 4) void bigstep_kernel(
        const float* __restrict__ base,
        const float* __restrict__ P,
        const float* __restrict__ V2g,
        const float* __restrict__ V3,
        const u64* __restrict__ rowbits,
        const u64* __restrict__ colbits,
        const float* __restrict__ Wnm,
        float* __restrict__ agg) {
    int i = blockIdx.x, b = blockIdx.y;
    int t = threadIdx.x;
    int w = t >> 6, l = t & 63;
    int ln = l & 15, grp = l >> 4;
    int bi = b * N + i;
    int bN = b * N;
    __shared__ float m2lds[4][16][68];   // per-wave [k_local][g] f32, padded
    __shared__ float red[4][F];
    __shared__ float v4buf[F];

    u64 rw = rowbits[bi * 4 + w];
    u64 cw = colbits[bi * 4 + w];
    u64 bothw = rw & cw;

    // A fragments: Wnm[m][g], m = 16ft+ln, g = 32ks+8grp+j  (hi/lo)
    bf16x8 Ah[8], Al[8];
#pragma unroll
    for (int ft = 0; ft < 4; ++ft) {
        const float4* wr = (const float4*)(Wnm + (size_t)(16 * ft + ln) * F);
#pragma unroll
        for (int ks = 0; ks < 2; ++ks) {
            float e[8];
            *(float4*)&e[0] = wr[8 * ks + 2 * grp];
            *(float4*)&e[4] = wr[8 * ks + 2 * grp + 1];
            build_frag(e, Ah[ft * 2 + ks], Al[ft * 2 + ks]);
        }
    }
    // V2[i] at this lane's g positions
    float v2f[2][8];
    {
        const float4* vr = (const float4*)(V2g + (size_t)bi * F);
#pragma unroll
        for (int ks = 0; ks < 2; ++ks) {
            *(float4*)&v2f[ks][0] = vr[8 * ks + 2 * grp];
            *(float4*)&v2f[ks][4] = vr[8 * ks + 2 * grp + 1];
        }
    }

    f32x4 acc2[4][4];   // [ft][kt] kept for agg
#pragma unroll
    for (int ft = 0; ft < 4; ++ft)
#pragma unroll
        for (int kt = 0; kt < 4; ++kt) acc2[ft][kt] = (f32x4){0.f, 0.f, 0.f, 0.f};

#pragma unroll
    for (int kt = 0; kt < 4; ++kt) {
        int kglob = w * 64 + kt * 16 + ln;
        // ---- GEMM1 (this kt) ----
        f32x4 acc1[4];
#pragma unroll
        for (int ft = 0; ft < 4; ++ft) acc1[ft] = (f32x4){0.f, 0.f, 0.f, 0.f};
        const float4* pr = (const float4*)(P + (size_t)(bN + kglob) * F);
#pragma unroll
        for (int ks = 0; ks < 2; ++ks) {
            float e[8];
            *(float4*)&e[0] = pr[8 * ks + 2 * grp];
            *(float4*)&e[4] = pr[8 * ks + 2 * grp + 1];
#pragma unroll
            for (int j = 0; j < 8; ++j) e[j] = fmaxf(v2f[ks][j] - e[j], 0.f);
            bf16x8 Bh, Bl;
            build_frag(e, Bh, Bl);
#pragma unroll
            for (int ft = 0; ft < 4; ++ft) {
                acc1[ft] = __builtin_amdgcn_mfma_f32_16x16x32_bf16(Ah[ft * 2 + ks], Bh, acc1[ft], 0, 0, 0);
                acc1[ft] = __builtin_amdgcn_mfma_f32_16x16x32_bf16(Ah[ft * 2 + ks], Bl, acc1[ft], 0, 0, 0);
                acc1[ft] = __builtin_amdgcn_mfma_f32_16x16x32_bf16(Al[ft * 2 + ks], Bh, acc1[ft], 0, 0, 0);
            }
        }
        // ---- M2 tile into LDS ----
        {
            float km = ((bothw >> (kt * 16 + ln)) & 1ull) ? 1.f : 0.f;
            const float* v3r = V3 + (size_t)(bN + kglob) * F;
#pragma unroll
            for (int ft = 0; ft < 4; ++ft) {
                int g0 = 16 * ft + 4 * grp;
                float4 v3v = *(const float4*)(v3r + g0);
                f32x4 tq = acc1[ft];
                float4 m2v;
                m2v.x = km * fmaxf(v3v.x - tq[0], 0.f);
                m2v.y = km * fmaxf(v3v.y - tq[1], 0.f);
                m2v.z = km * fmaxf(v3v.z - tq[2], 0.f);
                m2v.w = km * fmaxf(v3v.w - tq[3], 0.f);
                *(float4*)&m2lds[w][ln][g0] = m2v;
            }
        }
        // ---- GEMM2 (this kt) ----
#pragma unroll
        for (int ks = 0; ks < 2; ++ks) {
            int g0 = 32 * ks + 8 * grp;
            float e[8];
            *(float4*)&e[0] = *(const float4*)&m2lds[w][ln][g0];
            *(float4*)&e[4] = *(const float4*)&m2lds[w][ln][g0 + 4];
            bf16x8 Bh, Bl;
            build_frag(e, Bh, Bl);
#pragma unroll
            for (int ft = 0; ft < 4; ++ft) {
                acc2[ft][kt] = __builtin_amdgcn_mfma_f32_16x16x32_bf16(Ah[ft * 2 + ks], Bh, acc2[ft][kt], 0, 0, 0);
                acc2[ft][kt] = __builtin_amdgcn_mfma_f32_16x16x32_bf16(Ah[ft * 2 + ks], Bl, acc2[ft][kt], 0, 0, 0);
                acc2[ft][kt] = __builtin_amdgcn_mfma_f32_16x16x32_bf16(Al[ft * 2 + ks], Bh, acc2[ft][kt], 0, 0, 0);
            }
        }
    }

    // ---- S4 reduce ----
    float s4[4][4];
#pragma unroll
    for (int ft = 0; ft < 4; ++ft)
#pragma unroll
        for (int r = 0; r < 4; ++r)
            s4[ft][r] = acc2[ft][0][r] + acc2[ft][1][r] + acc2[ft][2][r] + acc2[ft][3][r];
#pragma unroll
    for (int m = 1; m <= 8; m <<= 1)
#pragma unroll
        for (int ft = 0; ft < 4; ++ft)
#pragma unroll
            for (int r = 0; r < 4; ++r)
                s4[ft][r] += __shfl_xor(s4[ft][r], m, 64);
    if (ln == 0) {
#pragma unroll
        for (int ft = 0; ft < 4; ++ft) {
            float4 q = make_float4(s4[ft][0], s4[ft][1], s4[ft][2], s4[ft][3]);
            *(float4*)&red[w][16 * ft + 4 * grp] = q;
        }
    }
    __syncthreads();
    if (t < F) v4buf[t] = base[(size_t)bi * F + t] + red[0][t] + red[1][t] + red[2][t] + red[3][t];
    __syncthreads();

    // ---- agg ----
    float v4r[4][4];
#pragma unroll
    for (int ft = 0; ft < 4; ++ft) {
        float4 q = *(const float4*)&v4buf[16 * ft + 4 * grp];
        v4r[ft][0] = q.x; v4r[ft][1] = q.y; v4r[ft][2] = q.z; v4r[ft][3] = q.w;
    }
    float av[4][4];
#pragma unroll
    for (int ft = 0; ft < 4; ++ft)
#pragma unroll
        for (int r = 0; r < 4; ++r) av[ft][r] = 0.f;
#pragma unroll
    for (int kt = 0; kt < 4; ++kt) {
        float rbm = ((rw >> (kt * 16 + ln)) & 1ull) ? 1.f : 0.f;
#pragma unroll
        for (int ft = 0; ft < 4; ++ft)
#pragma unroll
            for (int r = 0; r < 4; ++r)
                av[ft][r] += rbm * fmaxf(v4r[ft][r] - acc2[ft][kt][r], 0.f);
    }
#pragma unroll
    for (int m = 1; m <= 8; m <<= 1)
#pragma unroll
        for (int ft = 0; ft < 4; ++ft)
#pragma unroll
            for (int r = 0; r < 4; ++r)
                av[ft][r] += __shfl_xor(av[ft][r], m, 64);
    if (ln == 0) {
#pragma unroll
        for (int ft = 0; ft < 4; ++ft) {
            float4 q = make_float4(av[ft][0], av[ft][1], av[ft][2], av[ft][3]);
            *(float4*)&red[w][16 * ft + 4 * grp] = q;
        }
    }
    __syncthreads();
    if (t < F) agg[(size_t)bi * F + t] = red[0][t] + red[1][t] + red[2][t] + red[3][t];
}

// ---------------------------------------------------------------------------
// encode: enc = relu(Unf@X + Unm@agg); matvec tail split over 4 waves
// ---------------------------------------------------------------------------
__global__ __launch_bounds__(256) void encode_kernel(const float* __restrict__ X,
                                                     const float* __restrict__ Unf,
                                                     const float* __restrict__ Unm,
                                                     const float* __restrict__ agg,
                                                     float* __restrict__ enc) {
    int n = blockIdx.x, b = blockIdx.y;
    int t = threadIdx.x, w = t >> 6, f = t & 63;
    __shared__ float red[4][F];
    const float* urow = Unf + (size_t)n * N;
    const float* Xb = X + (size_t)b * N * F;
    float acc = 0.f;
    for (int j = 0; j < 64; ++j) {
        int m = w * 64 + j;
        acc += urow[m] * Xb[m * F + f];
    }
    red[w][f] = acc;
    __syncthreads();
    float msum = red[0][f] + red[1][f] + red[2][f] + red[3][f];
    __syncthreads();
    float ag = agg[((size_t)b * N + n) * F + f];
    float wv[16];
    const float4* wr = (const float4*)(Unm + (size_t)f * F + 16 * w);
#pragma unroll
    for (int q = 0; q < 4; ++q) *(float4*)&wv[q * 4] = wr[q];
    float a = 0.f;
#pragma unroll
    for (int q = 0; q < 16; ++q) a = fmaf(wv[q], __shfl(ag, 16 * w + q, 64), a);
    red[w][f] = a;
    __syncthreads();
    if (w == 0)
        enc[((size_t)b * N + n) * F + f] = fmaxf(msum + red[0][f] + red[1][f] + red[2][f] + red[3][f], 0.f);
}

// ---------------------------------------------------------------------------
// final: out[b,o] = sigmoid(enc_flat[b] . lw[o] + lb[o])   (float4 loads)
// ---------------------------------------------------------------------------
__global__ __launch_bounds__(256) void final_kernel(const float* __restrict__ enc,
                                                    const float* __restrict__ lw,
                                                    const float* __restrict__ lb,
                                                    float* __restrict__ out) {
    int o = blockIdx.x;
    int t = threadIdx.x;
    float acc[B];
#pragma unroll
    for (int b = 0; b < B; ++b) acc[b] = 0.f;
    const float4* lrow = (const float4*)(lw + (size_t)o * (N * F));
    const float4* e4 = (const float4*)enc;
    for (int k = t; k < (N * F) / 4; k += 256) {
        float4 wv = lrow[k];
#pragma unroll
        for (int b = 0; b < B; ++b) {
            float4 ev = e4[b * (N * F / 4) + k];
            acc[b] += wv.x * ev.x + wv.y * ev.y + wv.z * ev.z + wv.w * ev.w;
        }
    }
    __shared__ float red[B][256];
#pragma unroll
    for (int b = 0; b < B; ++b) red[b][t] = acc[b];
    __syncthreads();
    for (int off = 128; off > 0; off >>= 1) {
        if (t < off) {
#pragma unroll
            for (int b = 0; b < B; ++b) red[b][t] += red[b][t + off];
        }
        __syncthreads();
    }
    if (t < B) {
        float z = red[t][0] + lb[o];
        out[t * OUTD + o] = 1.f / (1.f + expf(-z));
    }
}

extern "C" void kernel_launch(void* const* d_in, const int* in_sizes, int n_in,
                              void* d_out, int out_size, void* d_ws, size_t ws_size,
                              hipStream_t stream) {
    const float* X   = (const float*)d_in[0];
    const int*   adj = (const int*)d_in[1];
    const float* Wnf = (const float*)d_in[2];
    const float* Wnm = (const float*)d_in[3];
    const float* Unf = (const float*)d_in[4];
    const float* Unm = (const float*)d_in[5];
    const float* lw  = (const float*)d_in[6];
    const float* lb  = (const float*)d_in[7];
    float* out = (float*)d_out;

    const long BNF = (long)B * N * F;
    u64* rowbits = (u64*)d_ws;
    u64* colbits = rowbits + (long)B * N * 4;
    float* fws = (float*)(colbits + (long)B * N * 4);
    float* base = fws;          fws += BNF;
    float* P    = fws;          fws += BNF;
    float* V2   = fws;          fws += BNF;
    float* V3   = fws;          fws += BNF;
    float* aggp = fws;          fws += BNF;
    float* enc  = fws;          fws += BNF;
    (void)ws_size; (void)in_sizes; (void)n_in; (void)out_size;

    prepA_kernel<<<dim3(64 + 64, B), 256, 0, stream>>>(adj, X, Wnf, Wnm, rowbits, base, P);
    v2B_kernel<<<dim3(N, B), 256, 0, stream>>>(base, P, rowbits, colbits, V2);
    s3_kernel<<<dim3(N, B), 256, 0, stream>>>(base, P, V2, rowbits, colbits, Wnm, V3);
    bigstep_kernel<<<dim3(N, B), 256, 0, stream>>>(base, P, V2, V3, rowbits, colbits, Wnm, aggp);
    encode_kernel<<<dim3(N, B), 256, 0, stream>>>(X, Unf, Unm, aggp, enc);
    final_kernel<<<OUTD, 256, 0, stream>>>(enc, lw, lb, out);
}

// Round 7
// 124.631 us; speedup vs baseline: 1.4739x; 1.4739x over previous
//
#include <hip/hip_runtime.h>
#include <hip/hip_bf16.h>
#include <math.h>

#define B 8
#define N 256
#define F 64
#define OUTD 256
typedef unsigned long long u64;
typedef __attribute__((ext_vector_type(8))) short bf16x8;
typedef __attribute__((ext_vector_type(4))) float f32x4;

// split x into hi+lo bf16 parts (truncation; residual <= 2^-16 |x|)
__device__ __forceinline__ void build_frag(const float* v8, bf16x8& h, bf16x8& l) {
#pragma unroll
    for (int j = 0; j < 8; ++j) {
        unsigned u = __float_as_uint(v8[j]);
        unsigned hb = u & 0xffff0000u;
        float r = v8[j] - __uint_as_float(hb);
        h[j] = (short)(hb >> 16);
        l[j] = (short)(__float_as_uint(r) >> 16);
    }
}

// ---------------------------------------------------------------------------
// A: fused pack_rows (bx<64) + prep (bx>=64). grid (64+64, B), 256 thr.
// ---------------------------------------------------------------------------
__global__ __launch_bounds__(256) void prepA_kernel(const int* __restrict__ adj,
                                                    const float* __restrict__ X,
                                                    const float* __restrict__ Wnf,
                                                    const float* __restrict__ Wnm,
                                                    u64* __restrict__ rowbits,
                                                    float* __restrict__ base,
                                                    float* __restrict__ P) {
    int b = blockIdx.y;
    int w = threadIdx.x >> 6;
    int lane = threadIdx.x & 63;
    if (blockIdx.x < 64) {
        int i = blockIdx.x * 4 + w;
#pragma unroll
        for (int wd = 0; wd < 4; ++wd) {
            int v = adj[(long)(b * N + i) * N + wd * 64 + lane];
            u64 bits = __ballot(v != 0);
            if (lane == 0) rowbits[(b * N + i) * 4 + wd] = bits;
        }
    } else {
        int n = (blockIdx.x - 64) * 4 + w;   // [0, 256)
        int bi = b * N + n;
        float x = X[(size_t)bi * F + lane];
        float acc = 0.f;
#pragma unroll
        for (int g = 0; g < F; ++g) acc = fmaf(Wnf[lane * F + g], __shfl(x, g, 64), acc);
        base[(size_t)bi * F + lane] = acc;
        float rs = fmaxf(acc, 0.f);
        float acc2 = 0.f;
#pragma unroll
        for (int g = 0; g < F; ++g) acc2 = fmaf(Wnm[lane * F + g], __shfl(rs, g, 64), acc2);
        P[(size_t)bi * F + lane] = acc2;
    }
}

// ---------------------------------------------------------------------------
// B: fused pack_cols + v2. grid (N, B), 256 thr.
// ---------------------------------------------------------------------------
__global__ __launch_bounds__(256) void v2B_kernel(const float* __restrict__ base,
                                                  const float* __restrict__ P,
                                                  const u64* __restrict__ rowbits,
                                                  u64* __restrict__ colbits,
                                                  float* __restrict__ V2) {
    int i = blockIdx.x, b = blockIdx.y;
    int t = threadIdx.x, w = t >> 6, f = t & 63;
    int bi = b * N + i;
    int bN = b * N;
    int iw = i >> 6, ib = i & 63;
    __shared__ float red[4][F];
    u64 rv = rowbits[(bN + w * 64 + f) * 4 + iw];
    u64 cw = __ballot((rv >> ib) & 1ull);
    if (f == 0) colbits[bi * 4 + w] = cw;
    u64 both = cw & rowbits[bi * 4 + w];
    const float* Pb = P + (size_t)bN * F;
    float acc = 0.f;
    for (int j = 0; j < 64; ++j) {
        float mk = ((both >> j) & 1ull) ? 1.f : 0.f;
        acc += mk * Pb[(w * 64 + j) * F + f];
    }
    red[w][f] = acc;
    __syncthreads();
    if (t < F) V2[(size_t)bi * F + t] = base[(size_t)bi * F + t] + red[0][t] + red[1][t] + red[2][t] + red[3][t];
}

// ---------------------------------------------------------------------------
// s3: V3[b,i] = base[b,i] + Wnm @ (sum_{k in both(i)} relu(V2[b,k]-P[b,i]))
// ---------------------------------------------------------------------------
__global__ __launch_bounds__(256) void s3_kernel(const float* __restrict__ base,
                                                 const float* __restrict__ P,
                                                 const float* __restrict__ V2g,
                                                 const u64* __restrict__ rowbits,
                                                 const u64* __restrict__ colbits,
                                                 const float* __restrict__ Wnm,
                                                 float* __restrict__ V3) {
    int i = blockIdx.x, b = blockIdx.y;
    int t = threadIdx.x, w = t >> 6, f = t & 63;
    int bi = b * N + i;
    __shared__ float red[4][F];
    u64 both = rowbits[bi * 4 + w] & colbits[bi * 4 + w];
    float pif = P[(size_t)bi * F + f];
    const float* Vb = V2g + (size_t)b * N * F;
    float acc = 0.f;
    for (int j = 0; j < 64; ++j) {
        float mk = ((both >> j) & 1ull) ? 1.f : 0.f;
        acc += mk * fmaxf(Vb[(w * 64 + j) * F + f] - pif, 0.f);
    }
    red[w][f] = acc;
    __syncthreads();
    float u = red[0][f] + red[1][f] + red[2][f] + red[3][f];
    __syncthreads();
    float wv[16];
    const float4* wr = (const float4*)(Wnm + (size_t)f * F + 16 * w);
#pragma unroll
    for (int q = 0; q < 4; ++q) *(float4*)&wv[q * 4] = wr[q];
    float a = 0.f;
#pragma unroll
    for (int q = 0; q < 16; ++q) a = fmaf(wv[q], __shfl(u, 16 * w + q, 64), a);
    red[w][f] = a;
    __syncthreads();
    if (t < F) V3[(size_t)bi * F + t] = base[(size_t)bi * F + t] + red[0][t] + red[1][t] + red[2][t] + red[3][t];
}

// ---------------------------------------------------------------------------
// bigstep via MFMA (hi/lo bf16 3-pass ~ fp32), per-kt LDS phasing (17.4 KB).
// __launch_bounds__(256,2): VGPR cap 256 -> no accumulator spill (r6 lesson:
// (256,4) capped VGPR at 64 and spilled acc2 -> 475 MB scratch traffic).
// ---------------------------------------------------------------------------
__global__ __launch_bounds__(256, 2) void bigstep_kernel(
        const float* __restrict__ base,
        const float* __restrict__ P,
        const float* __restrict__ V2g,
        const float* __restrict__ V3,
        const u64* __restrict__ rowbits,
        const u64* __restrict__ colbits,
        const float* __restrict__ Wnm,
        float* __restrict__ agg) {
    int i = blockIdx.x, b = blockIdx.y;
    int t = threadIdx.x;
    int w = t >> 6, l = t & 63;
    int ln = l & 15, grp = l >> 4;
    int bi = b * N + i;
    int bN = b * N;
    __shared__ float m2lds[4][16][68];   // per-wave [k_local][g] f32, padded
    __shared__ float red[4][F];
    __shared__ float v4buf[F];

    u64 rw = rowbits[bi * 4 + w];
    u64 cw = colbits[bi * 4 + w];
    u64 bothw = rw & cw;

    // A fragments: Wnm[m][g], m = 16ft+ln, g = 32ks+8grp+j  (hi/lo)
    bf16x8 Ah[8], Al[8];
#pragma unroll
    for (int ft = 0; ft < 4; ++ft) {
        const float4* wr = (const float4*)(Wnm + (size_t)(16 * ft + ln) * F);
#pragma unroll
        for (int ks = 0; ks < 2; ++ks) {
            float e[8];
            *(float4*)&e[0] = wr[8 * ks + 2 * grp];
            *(float4*)&e[4] = wr[8 * ks + 2 * grp + 1];
            build_frag(e, Ah[ft * 2 + ks], Al[ft * 2 + ks]);
        }
    }
    // V2[i] at this lane's g positions
    float v2f[2][8];
    {
        const float4* vr = (const float4*)(V2g + (size_t)bi * F);
#pragma unroll
        for (int ks = 0; ks < 2; ++ks) {
            *(float4*)&v2f[ks][0] = vr[8 * ks + 2 * grp];
            *(float4*)&v2f[ks][4] = vr[8 * ks + 2 * grp + 1];
        }
    }

    f32x4 acc2[4][4];   // [ft][kt] kept for agg
#pragma unroll
    for (int ft = 0; ft < 4; ++ft)
#pragma unroll
        for (int kt = 0; kt < 4; ++kt) acc2[ft][kt] = (f32x4){0.f, 0.f, 0.f, 0.f};

#pragma unroll
    for (int kt = 0; kt < 4; ++kt) {
        int kglob = w * 64 + kt * 16 + ln;
        // ---- GEMM1 (this kt) ----
        f32x4 acc1[4];
#pragma unroll
        for (int ft = 0; ft < 4; ++ft) acc1[ft] = (f32x4){0.f, 0.f, 0.f, 0.f};
        const float4* pr = (const float4*)(P + (size_t)(bN + kglob) * F);
#pragma unroll
        for (int ks = 0; ks < 2; ++ks) {
            float e[8];
            *(float4*)&e[0] = pr[8 * ks + 2 * grp];
            *(float4*)&e[4] = pr[8 * ks + 2 * grp + 1];
#pragma unroll
            for (int j = 0; j < 8; ++j) e[j] = fmaxf(v2f[ks][j] - e[j], 0.f);
            bf16x8 Bh, Bl;
            build_frag(e, Bh, Bl);
#pragma unroll
            for (int ft = 0; ft < 4; ++ft) {
                acc1[ft] = __builtin_amdgcn_mfma_f32_16x16x32_bf16(Ah[ft * 2 + ks], Bh, acc1[ft], 0, 0, 0);
                acc1[ft] = __builtin_amdgcn_mfma_f32_16x16x32_bf16(Ah[ft * 2 + ks], Bl, acc1[ft], 0, 0, 0);
                acc1[ft] = __builtin_amdgcn_mfma_f32_16x16x32_bf16(Al[ft * 2 + ks], Bh, acc1[ft], 0, 0, 0);
            }
        }
        // ---- M2 tile into LDS ----
        {
            float km = ((bothw >> (kt * 16 + ln)) & 1ull) ? 1.f : 0.f;
            const float* v3r = V3 + (size_t)(bN + kglob) * F;
#pragma unroll
            for (int ft = 0; ft < 4; ++ft) {
                int g0 = 16 * ft + 4 * grp;
                float4 v3v = *(const float4*)(v3r + g0);
                f32x4 tq = acc1[ft];
                float4 m2v;
                m2v.x = km * fmaxf(v3v.x - tq[0], 0.f);
                m2v.y = km * fmaxf(v3v.y - tq[1], 0.f);
                m2v.z = km * fmaxf(v3v.z - tq[2], 0.f);
                m2v.w = km * fmaxf(v3v.w - tq[3], 0.f);
                *(float4*)&m2lds[w][ln][g0] = m2v;
            }
        }
        // ---- GEMM2 (this kt) ----
#pragma unroll
        for (int ks = 0; ks < 2; ++ks) {
            int g0 = 32 * ks + 8 * grp;
            float e[8];
            *(float4*)&e[0] = *(const float4*)&m2lds[w][ln][g0];
            *(float4*)&e[4] = *(const float4*)&m2lds[w][ln][g0 + 4];
            bf16x8 Bh, Bl;
            build_frag(e, Bh, Bl);
#pragma unroll
            for (int ft = 0; ft < 4; ++ft) {
                acc2[ft][kt] = __builtin_amdgcn_mfma_f32_16x16x32_bf16(Ah[ft * 2 + ks], Bh, acc2[ft][kt], 0, 0, 0);
                acc2[ft][kt] = __builtin_amdgcn_mfma_f32_16x16x32_bf16(Ah[ft * 2 + ks], Bl, acc2[ft][kt], 0, 0, 0);
                acc2[ft][kt] = __builtin_amdgcn_mfma_f32_16x16x32_bf16(Al[ft * 2 + ks], Bh, acc2[ft][kt], 0, 0, 0);
            }
        }
    }

    // ---- S4 reduce ----
    float s4[4][4];
#pragma unroll
    for (int ft = 0; ft < 4; ++ft)
#pragma unroll
        for (int r = 0; r < 4; ++r)
            s4[ft][r] = acc2[ft][0][r] + acc2[ft][1][r] + acc2[ft][2][r] + acc2[ft][3][r];
#pragma unroll
    for (int m = 1; m <= 8; m <<= 1)
#pragma unroll
        for (int ft = 0; ft < 4; ++ft)
#pragma unroll
            for (int r = 0; r < 4; ++r)
                s4[ft][r] += __shfl_xor(s4[ft][r], m, 64);
    if (ln == 0) {
#pragma unroll
        for (int ft = 0; ft < 4; ++ft) {
            float4 q = make_float4(s4[ft][0], s4[ft][1], s4[ft][2], s4[ft][3]);
            *(float4*)&red[w][16 * ft + 4 * grp] = q;
        }
    }
    __syncthreads();
    if (t < F) v4buf[t] = base[(size_t)bi * F + t] + red[0][t] + red[1][t] + red[2][t] + red[3][t];
    __syncthreads();

    // ---- agg ----
    float v4r[4][4];
#pragma unroll
    for (int ft = 0; ft < 4; ++ft) {
        float4 q = *(const float4*)&v4buf[16 * ft + 4 * grp];
        v4r[ft][0] = q.x; v4r[ft][1] = q.y; v4r[ft][2] = q.z; v4r[ft][3] = q.w;
    }
    float av[4][4];
#pragma unroll
    for (int ft = 0; ft < 4; ++ft)
#pragma unroll
        for (int r = 0; r < 4; ++r) av[ft][r] = 0.f;
#pragma unroll
    for (int kt = 0; kt < 4; ++kt) {
        float rbm = ((rw >> (kt * 16 + ln)) & 1ull) ? 1.f : 0.f;
#pragma unroll
        for (int ft = 0; ft < 4; ++ft)
#pragma unroll
            for (int r = 0; r < 4; ++r)
                av[ft][r] += rbm * fmaxf(v4r[ft][r] - acc2[ft][kt][r], 0.f);
    }
#pragma unroll
    for (int m = 1; m <= 8; m <<= 1)
#pragma unroll
        for (int ft = 0; ft < 4; ++ft)
#pragma unroll
            for (int r = 0; r < 4; ++r)
                av[ft][r] += __shfl_xor(av[ft][r], m, 64);
    if (ln == 0) {
#pragma unroll
        for (int ft = 0; ft < 4; ++ft) {
            float4 q = make_float4(av[ft][0], av[ft][1], av[ft][2], av[ft][3]);
            *(float4*)&red[w][16 * ft + 4 * grp] = q;
        }
    }
    __syncthreads();
    if (t < F) agg[(size_t)bi * F + t] = red[0][t] + red[1][t] + red[2][t] + red[3][t];
}

// ---------------------------------------------------------------------------
// encode: enc = relu(Unf@X + Unm@agg); matvec tail split over 4 waves
// ---------------------------------------------------------------------------
__global__ __launch_bounds__(256) void encode_kernel(const float* __restrict__ X,
                                                     const float* __restrict__ Unf,
                                                     const float* __restrict__ Unm,
                                                     const float* __restrict__ agg,
                                                     float* __restrict__ enc) {
    int n = blockIdx.x, b = blockIdx.y;
    int t = threadIdx.x, w = t >> 6, f = t & 63;
    __shared__ float red[4][F];
    const float* urow = Unf + (size_t)n * N;
    const float* Xb = X + (size_t)b * N * F;
    float acc = 0.f;
    for (int j = 0; j < 64; ++j) {
        int m = w * 64 + j;
        acc += urow[m] * Xb[m * F + f];
    }
    red[w][f] = acc;
    __syncthreads();
    float msum = red[0][f] + red[1][f] + red[2][f] + red[3][f];
    __syncthreads();
    float ag = agg[((size_t)b * N + n) * F + f];
    float wv[16];
    const float4* wr = (const float4*)(Unm + (size_t)f * F + 16 * w);
#pragma unroll
    for (int q = 0; q < 4; ++q) *(float4*)&wv[q * 4] = wr[q];
    float a = 0.f;
#pragma unroll
    for (int q = 0; q < 16; ++q) a = fmaf(wv[q], __shfl(ag, 16 * w + q, 64), a);
    red[w][f] = a;
    __syncthreads();
    if (w == 0)
        enc[((size_t)b * N + n) * F + f] = fmaxf(msum + red[0][f] + red[1][f] + red[2][f] + red[3][f], 0.f);
}

// ---------------------------------------------------------------------------
// final: out[b,o] = sigmoid(enc_flat[b] . lw[o] + lb[o])   (float4 loads)
// ---------------------------------------------------------------------------
__global__ __launch_bounds__(256) void final_kernel(const float* __restrict__ enc,
                                                    const float* __restrict__ lw,
                                                    const float* __restrict__ lb,
                                                    float* __restrict__ out) {
    int o = blockIdx.x;
    int t = threadIdx.x;
    float acc[B];
#pragma unroll
    for (int b = 0; b < B; ++b) acc[b] = 0.f;
    const float4* lrow = (const float4*)(lw + (size_t)o * (N * F));
    const float4* e4 = (const float4*)enc;
    for (int k = t; k < (N * F) / 4; k += 256) {
        float4 wv = lrow[k];
#pragma unroll
        for (int b = 0; b < B; ++b) {
            float4 ev = e4[b * (N * F / 4) + k];
            acc[b] += wv.x * ev.x + wv.y * ev.y + wv.z * ev.z + wv.w * ev.w;
        }
    }
    __shared__ float red[B][256];
#pragma unroll
    for (int b = 0; b < B; ++b) red[b][t] = acc[b];
    __syncthreads();
    for (int off = 128; off > 0; off >>= 1) {
        if (t < off) {
#pragma unroll
            for (int b = 0; b < B; ++b) red[b][t] += red[b][t + off];
        }
        __syncthreads();
    }
    if (t < B) {
        float z = red[t][0] + lb[o];
        out[t * OUTD + o] = 1.f / (1.f + expf(-z));
    }
}

extern "C" void kernel_launch(void* const* d_in, const int* in_sizes, int n_in,
                              void* d_out, int out_size, void* d_ws, size_t ws_size,
                              hipStream_t stream) {
    const float* X   = (const float*)d_in[0];
    const int*   adj = (const int*)d_in[1];
    const float* Wnf = (const float*)d_in[2];
    const float* Wnm = (const float*)d_in[3];
    const float* Unf = (const float*)d_in[4];
    const float* Unm = (const float*)d_in[5];
    const float* lw  = (const float*)d_in[6];
    const float* lb  = (const float*)d_in[7];
    float* out = (float*)d_out;

    const long BNF = (long)B * N * F;
    u64* rowbits = (u64*)d_ws;
    u64* colbits = rowbits + (long)B * N * 4;
    float* fws = (float*)(colbits + (long)B * N * 4);
    float* base = fws;          fws += BNF;
    float* P    = fws;          fws += BNF;
    float* V2   = fws;          fws += BNF;
    float* V3   = fws;          fws += BNF;
    float* aggp = fws;          fws += BNF;
    float* enc  = fws;          fws += BNF;
    (void)ws_size; (void)in_sizes; (void)n_in; (void)out_size;

    prepA_kernel<<<dim3(64 + 64, B), 256, 0, stream>>>(adj, X, Wnf, Wnm, rowbits, base, P);
    v2B_kernel<<<dim3(N, B), 256, 0, stream>>>(base, P, rowbits, colbits, V2);
    s3_kernel<<<dim3(N, B), 256, 0, stream>>>(base, P, V2, rowbits, colbits, Wnm, V3);
    bigstep_kernel<<<dim3(N, B), 256, 0, stream>>>(base, P, V2, V3, rowbits, colbits, Wnm, aggp);
    encode_kernel<<<dim3(N, B), 256, 0, stream>>>(X, Unf, Unm, aggp, enc);
    final_kernel<<<OUTD, 256, 0, stream>>>(enc, lw, lb, out);
}

// Round 10
// 124.563 us; speedup vs baseline: 1.4747x; 1.0005x over previous
//
#include <hip/hip_runtime.h>
#include <hip/hip_bf16.h>
#include <math.h>

#define B 8
#define N 256
#define F 64
#define OUTD 256
typedef unsigned long long u64;
typedef __attribute__((ext_vector_type(8))) short bf16x8;
typedef __attribute__((ext_vector_type(4))) float f32x4;

// split x into hi+lo bf16 parts (truncation; residual <= 2^-16 |x|)
__device__ __forceinline__ void build_frag(const float* v8, bf16x8& h, bf16x8& l) {
#pragma unroll
    for (int j = 0; j < 8; ++j) {
        unsigned u = __float_as_uint(v8[j]);
        unsigned hb = u & 0xffff0000u;
        float r = v8[j] - __uint_as_float(hb);
        h[j] = (short)(hb >> 16);
        l[j] = (short)(__float_as_uint(r) >> 16);
    }
}

// ---------------------------------------------------------------------------
// A: fused pack_rows (bx<64) + prep (bx>=64). grid (64+64, B), 256 thr.
// ---------------------------------------------------------------------------
__global__ __launch_bounds__(256) void prepA_kernel(const int* __restrict__ adj,
                                                    const float* __restrict__ X,
                                                    const float* __restrict__ Wnf,
                                                    const float* __restrict__ Wnm,
                                                    u64* __restrict__ rowbits,
                                                    float* __restrict__ base,
                                                    float* __restrict__ P) {
    int b = blockIdx.y;
    int w = threadIdx.x >> 6;
    int lane = threadIdx.x & 63;
    if (blockIdx.x < 64) {
        int i = blockIdx.x * 4 + w;
#pragma unroll
        for (int wd = 0; wd < 4; ++wd) {
            int v = adj[(long)(b * N + i) * N + wd * 64 + lane];
            u64 bits = __ballot(v != 0);
            if (lane == 0) rowbits[(b * N + i) * 4 + wd] = bits;
        }
    } else {
        int n = (blockIdx.x - 64) * 4 + w;   // [0, 256)
        int bi = b * N + n;
        float x = X[(size_t)bi * F + lane];
        float acc = 0.f;
#pragma unroll
        for (int g = 0; g < F; ++g) acc = fmaf(Wnf[lane * F + g], __shfl(x, g, 64), acc);
        base[(size_t)bi * F + lane] = acc;
        float rs = fmaxf(acc, 0.f);
        float acc2 = 0.f;
#pragma unroll
        for (int g = 0; g < F; ++g) acc2 = fmaf(Wnm[lane * F + g], __shfl(rs, g, 64), acc2);
        P[(size_t)bi * F + lane] = acc2;
    }
}

// ---------------------------------------------------------------------------
// B: fused pack_cols + v2. grid (N, B), 256 thr.
// ---------------------------------------------------------------------------
__global__ __launch_bounds__(256) void v2B_kernel(const float* __restrict__ base,
                                                  const float* __restrict__ P,
                                                  const u64* __restrict__ rowbits,
                                                  u64* __restrict__ colbits,
                                                  float* __restrict__ V2) {
    int i = blockIdx.x, b = blockIdx.y;
    int t = threadIdx.x, w = t >> 6, f = t & 63;
    int bi = b * N + i;
    int bN = b * N;
    int iw = i >> 6, ib = i & 63;
    __shared__ float red[4][F];
    u64 rv = rowbits[(bN + w * 64 + f) * 4 + iw];
    u64 cw = __ballot((rv >> ib) & 1ull);
    if (f == 0) colbits[bi * 4 + w] = cw;
    u64 both = cw & rowbits[bi * 4 + w];
    const float* Pb = P + (size_t)bN * F;
    float acc = 0.f;
    for (int j = 0; j < 64; ++j) {
        float mk = ((both >> j) & 1ull) ? 1.f : 0.f;
        acc += mk * Pb[(w * 64 + j) * F + f];
    }
    red[w][f] = acc;
    __syncthreads();
    if (t < F) V2[(size_t)bi * F + t] = base[(size_t)bi * F + t] + red[0][t] + red[1][t] + red[2][t] + red[3][t];
}

// ---------------------------------------------------------------------------
// s3: V3[b,i] = base[b,i] + Wnm @ (sum_{k in both(i)} relu(V2[b,k]-P[b,i]))
// ---------------------------------------------------------------------------
__global__ __launch_bounds__(256) void s3_kernel(const float* __restrict__ base,
                                                 const float* __restrict__ P,
                                                 const float* __restrict__ V2g,
                                                 const u64* __restrict__ rowbits,
                                                 const u64* __restrict__ colbits,
                                                 const float* __restrict__ Wnm,
                                                 float* __restrict__ V3) {
    int i = blockIdx.x, b = blockIdx.y;
    int t = threadIdx.x, w = t >> 6, f = t & 63;
    int bi = b * N + i;
    __shared__ float red[4][F];
    u64 both = rowbits[bi * 4 + w] & colbits[bi * 4 + w];
    float pif = P[(size_t)bi * F + f];
    const float* Vb = V2g + (size_t)b * N * F;
    float acc = 0.f;
    for (int j = 0; j < 64; ++j) {
        float mk = ((both >> j) & 1ull) ? 1.f : 0.f;
        acc += mk * fmaxf(Vb[(w * 64 + j) * F + f] - pif, 0.f);
    }
    red[w][f] = acc;
    __syncthreads();
    float u = red[0][f] + red[1][f] + red[2][f] + red[3][f];
    __syncthreads();
    float wv[16];
    const float4* wr = (const float4*)(Wnm + (size_t)f * F + 16 * w);
#pragma unroll
    for (int q = 0; q < 4; ++q) *(float4*)&wv[q * 4] = wr[q];
    float a = 0.f;
#pragma unroll
    for (int q = 0; q < 16; ++q) a = fmaf(wv[q], __shfl(u, 16 * w + q, 64), a);
    red[w][f] = a;
    __syncthreads();
    if (t < F) V3[(size_t)bi * F + t] = base[(size_t)bi * F + t] + red[0][t] + red[1][t] + red[2][t] + red[3][t];
}

// ---------------------------------------------------------------------------
// bigstep via MFMA (hi/lo bf16 3-pass ~ fp32), per-kt LDS phasing (17.4 KB).
// __launch_bounds__(256,2): VGPR cap 256 -> no accumulator spill.
// NOTE: r8/r9 showed data-dependent branches around this MFMA+LDS cluster
// cause launch-level failure -> keep the kt loop branch-free.
// ---------------------------------------------------------------------------
__global__ __launch_bounds__(256, 2) void bigstep_kernel(
        const float* __restrict__ base,
        const float* __restrict__ P,
        const float* __restrict__ V2g,
        const float* __restrict__ V3,
        const u64* __restrict__ rowbits,
        const u64* __restrict__ colbits,
        const float* __restrict__ Wnm,
        float* __restrict__ agg) {
    int i = blockIdx.x, b = blockIdx.y;
    int t = threadIdx.x;
    int w = t >> 6, l = t & 63;
    int ln = l & 15, grp = l >> 4;
    int bi = b * N + i;
    int bN = b * N;
    __shared__ float m2lds[4][16][68];   // per-wave [k_local][g] f32, padded
    __shared__ float red[4][F];
    __shared__ float v4buf[F];

    u64 rw = rowbits[bi * 4 + w];
    u64 cw = colbits[bi * 4 + w];
    u64 bothw = rw & cw;

    // A fragments: Wnm[m][g], m = 16ft+ln, g = 32ks+8grp+j  (hi/lo)
    bf16x8 Ah[8], Al[8];
#pragma unroll
    for (int ft = 0; ft < 4; ++ft) {
        const float4* wr = (const float4*)(Wnm + (size_t)(16 * ft + ln) * F);
#pragma unroll
        for (int ks = 0; ks < 2; ++ks) {
            float e[8];
            *(float4*)&e[0] = wr[8 * ks + 2 * grp];
            *(float4*)&e[4] = wr[8 * ks + 2 * grp + 1];
            build_frag(e, Ah[ft * 2 + ks], Al[ft * 2 + ks]);
        }
    }
    // V2[i] at this lane's g positions
    float v2f[2][8];
    {
        const float4* vr = (const float4*)(V2g + (size_t)bi * F);
#pragma unroll
        for (int ks = 0; ks < 2; ++ks) {
            *(float4*)&v2f[ks][0] = vr[8 * ks + 2 * grp];
            *(float4*)&v2f[ks][4] = vr[8 * ks + 2 * grp + 1];
        }
    }

    f32x4 acc2[4][4];   // [ft][kt] kept for agg
#pragma unroll
    for (int ft = 0; ft < 4; ++ft)
#pragma unroll
        for (int kt = 0; kt < 4; ++kt) acc2[ft][kt] = (f32x4){0.f, 0.f, 0.f, 0.f};

#pragma unroll
    for (int kt = 0; kt < 4; ++kt) {
        int kglob = w * 64 + kt * 16 + ln;
        // ---- GEMM1 (this kt) ----
        f32x4 acc1[4];
#pragma unroll
        for (int ft = 0; ft < 4; ++ft) acc1[ft] = (f32x4){0.f, 0.f, 0.f, 0.f};
        const float4* pr = (const float4*)(P + (size_t)(bN + kglob) * F);
#pragma unroll
        for (int ks = 0; ks < 2; ++ks) {
            float e[8];
            *(float4*)&e[0] = pr[8 * ks + 2 * grp];
            *(float4*)&e[4] = pr[8 * ks + 2 * grp + 1];
#pragma unroll
            for (int j = 0; j < 8; ++j) e[j] = fmaxf(v2f[ks][j] - e[j], 0.f);
            bf16x8 Bh, Bl;
            build_frag(e, Bh, Bl);
#pragma unroll
            for (int ft = 0; ft < 4; ++ft) {
                acc1[ft] = __builtin_amdgcn_mfma_f32_16x16x32_bf16(Ah[ft * 2 + ks], Bh, acc1[ft], 0, 0, 0);
                acc1[ft] = __builtin_amdgcn_mfma_f32_16x16x32_bf16(Ah[ft * 2 + ks], Bl, acc1[ft], 0, 0, 0);
                acc1[ft] = __builtin_amdgcn_mfma_f32_16x16x32_bf16(Al[ft * 2 + ks], Bh, acc1[ft], 0, 0, 0);
            }
        }
        // ---- M2 tile into LDS ----
        {
            float km = ((bothw >> (kt * 16 + ln)) & 1ull) ? 1.f : 0.f;
            const float* v3r = V3 + (size_t)(bN + kglob) * F;
#pragma unroll
            for (int ft = 0; ft < 4; ++ft) {
                int g0 = 16 * ft + 4 * grp;
                float4 v3v = *(const float4*)(v3r + g0);
                f32x4 tq = acc1[ft];
                float4 m2v;
                m2v.x = km * fmaxf(v3v.x - tq[0], 0.f);
                m2v.y = km * fmaxf(v3v.y - tq[1], 0.f);
                m2v.z = km * fmaxf(v3v.z - tq[2], 0.f);
                m2v.w = km * fmaxf(v3v.w - tq[3], 0.f);
                *(float4*)&m2lds[w][ln][g0] = m2v;
            }
        }
        // ---- GEMM2 (this kt) ----
#pragma unroll
        for (int ks = 0; ks < 2; ++ks) {
            int g0 = 32 * ks + 8 * grp;
            float e[8];
            *(float4*)&e[0] = *(const float4*)&m2lds[w][ln][g0];
            *(float4*)&e[4] = *(const float4*)&m2lds[w][ln][g0 + 4];
            bf16x8 Bh, Bl;
            build_frag(e, Bh, Bl);
#pragma unroll
            for (int ft = 0; ft < 4; ++ft) {
                acc2[ft][kt] = __builtin_amdgcn_mfma_f32_16x16x32_bf16(Ah[ft * 2 + ks], Bh, acc2[ft][kt], 0, 0, 0);
                acc2[ft][kt] = __builtin_amdgcn_mfma_f32_16x16x32_bf16(Ah[ft * 2 + ks], Bl, acc2[ft][kt], 0, 0, 0);
                acc2[ft][kt] = __builtin_amdgcn_mfma_f32_16x16x32_bf16(Al[ft * 2 + ks], Bh, acc2[ft][kt], 0, 0, 0);
            }
        }
    }

    // ---- S4 reduce ----
    float s4[4][4];
#pragma unroll
    for (int ft = 0; ft < 4; ++ft)
#pragma unroll
        for (int r = 0; r < 4; ++r)
            s4[ft][r] = acc2[ft][0][r] + acc2[ft][1][r] + acc2[ft][2][r] + acc2[ft][3][r];
#pragma unroll
    for (int m = 1; m <= 8; m <<= 1)
#pragma unroll
        for (int ft = 0; ft < 4; ++ft)
#pragma unroll
            for (int r = 0; r < 4; ++r)
                s4[ft][r] += __shfl_xor(s4[ft][r], m, 64);
    if (ln == 0) {
#pragma unroll
        for (int ft = 0; ft < 4; ++ft) {
            float4 q = make_float4(s4[ft][0], s4[ft][1], s4[ft][2], s4[ft][3]);
            *(float4*)&red[w][16 * ft + 4 * grp] = q;
        }
    }
    __syncthreads();
    if (t < F) v4buf[t] = base[(size_t)bi * F + t] + red[0][t] + red[1][t] + red[2][t] + red[3][t];
    __syncthreads();

    // ---- agg ----
    float v4r[4][4];
#pragma unroll
    for (int ft = 0; ft < 4; ++ft) {
        float4 q = *(const float4*)&v4buf[16 * ft + 4 * grp];
        v4r[ft][0] = q.x; v4r[ft][1] = q.y; v4r[ft][2] = q.z; v4r[ft][3] = q.w;
    }
    float av[4][4];
#pragma unroll
    for (int ft = 0; ft < 4; ++ft)
#pragma unroll
        for (int r = 0; r < 4; ++r) av[ft][r] = 0.f;
#pragma unroll
    for (int kt = 0; kt < 4; ++kt) {
        float rbm = ((rw >> (kt * 16 + ln)) & 1ull) ? 1.f : 0.f;
#pragma unroll
        for (int ft = 0; ft < 4; ++ft)
#pragma unroll
            for (int r = 0; r < 4; ++r)
                av[ft][r] += rbm * fmaxf(v4r[ft][r] - acc2[ft][kt][r], 0.f);
    }
#pragma unroll
    for (int m = 1; m <= 8; m <<= 1)
#pragma unroll
        for (int ft = 0; ft < 4; ++ft)
#pragma unroll
            for (int r = 0; r < 4; ++r)
                av[ft][r] += __shfl_xor(av[ft][r], m, 64);
    if (ln == 0) {
#pragma unroll
        for (int ft = 0; ft < 4; ++ft) {
            float4 q = make_float4(av[ft][0], av[ft][1], av[ft][2], av[ft][3]);
            *(float4*)&red[w][16 * ft + 4 * grp] = q;
        }
    }
    __syncthreads();
    if (t < F) agg[(size_t)bi * F + t] = red[0][t] + red[1][t] + red[2][t] + red[3][t];
}

// ---------------------------------------------------------------------------
// encode: enc = relu(Unf@X + Unm@agg); matvec tail split over 4 waves
// ---------------------------------------------------------------------------
__global__ __launch_bounds__(256) void encode_kernel(const float* __restrict__ X,
                                                     const float* __restrict__ Unf,
                                                     const float* __restrict__ Unm,
                                                     const float* __restrict__ agg,
                                                     float* __restrict__ enc) {
    int n = blockIdx.x, b = blockIdx.y;
    int t = threadIdx.x, w = t >> 6, f = t & 63;
    __shared__ float red[4][F];
    const float* urow = Unf + (size_t)n * N;
    const float* Xb = X + (size_t)b * N * F;
    float acc = 0.f;
    for (int j = 0; j < 64; ++j) {
        int m = w * 64 + j;
        acc += urow[m] * Xb[m * F + f];
    }
    red[w][f] = acc;
    __syncthreads();
    float msum = red[0][f] + red[1][f] + red[2][f] + red[3][f];
    __syncthreads();
    float ag = agg[((size_t)b * N + n) * F + f];
    float wv[16];
    const float4* wr = (const float4*)(Unm + (size_t)f * F + 16 * w);
#pragma unroll
    for (int q = 0; q < 4; ++q) *(float4*)&wv[q * 4] = wr[q];
    float a = 0.f;
#pragma unroll
    for (int q = 0; q < 16; ++q) a = fmaf(wv[q], __shfl(ag, 16 * w + q, 64), a);
    red[w][f] = a;
    __syncthreads();
    if (w == 0)
        enc[((size_t)b * N + n) * F + f] = fmaxf(msum + red[0][f] + red[1][f] + red[2][f] + red[3][f], 0.f);
}

// ---------------------------------------------------------------------------
// final: out[b,o] = sigmoid(enc_flat[b] . lw[o] + lb[o])   (float4 loads)
// ---------------------------------------------------------------------------
__global__ __launch_bounds__(256) void final_kernel(const float* __restrict__ enc,
                                                    const float* __restrict__ lw,
                                                    const float* __restrict__ lb,
                                                    float* __restrict__ out) {
    int o = blockIdx.x;
    int t = threadIdx.x;
    float acc[B];
#pragma unroll
    for (int b = 0; b < B; ++b) acc[b] = 0.f;
    const float4* lrow = (const float4*)(lw + (size_t)o * (N * F));
    const float4* e4 = (const float4*)enc;
    for (int k = t; k < (N * F) / 4; k += 256) {
        float4 wv = lrow[k];
#pragma unroll
        for (int b = 0; b < B; ++b) {
            float4 ev = e4[b * (N * F / 4) + k];
            acc[b] += wv.x * ev.x + wv.y * ev.y + wv.z * ev.z + wv.w * ev.w;
        }
    }
    __shared__ float red[B][256];
#pragma unroll
    for (int b = 0; b < B; ++b) red[b][t] = acc[b];
    __syncthreads();
    for (int off = 128; off > 0; off >>= 1) {
        if (t < off) {
#pragma unroll
            for (int b = 0; b < B; ++b) red[b][t] += red[b][t + off];
        }
        __syncthreads();
    }
    if (t < B) {
        float z = red[t][0] + lb[o];
        out[t * OUTD + o] = 1.f / (1.f + expf(-z));
    }
}

extern "C" void kernel_launch(void* const* d_in, const int* in_sizes, int n_in,
                              void* d_out, int out_size, void* d_ws, size_t ws_size,
                              hipStream_t stream) {
    const float* X   = (const float*)d_in[0];
    const int*   adj = (const int*)d_in[1];
    const float* Wnf = (const float*)d_in[2];
    const float* Wnm = (const float*)d_in[3];
    const float* Unf = (const float*)d_in[4];
    const float* Unm = (const float*)d_in[5];
    const float* lw  = (const float*)d_in[6];
    const float* lb  = (const float*)d_in[7];
    float* out = (float*)d_out;

    const long BNF = (long)B * N * F;
    u64* rowbits = (u64*)d_ws;
    u64* colbits = rowbits + (long)B * N * 4;
    float* fws = (float*)(colbits + (long)B * N * 4);
    float* base = fws;          fws += BNF;
    float* P    = fws;          fws += BNF;
    float* V2   = fws;          fws += BNF;
    float* V3   = fws;          fws += BNF;
    float* aggp = fws;          fws += BNF;
    float* enc  = fws;          fws += BNF;
    (void)ws_size; (void)in_sizes; (void)n_in; (void)out_size;

    prepA_kernel<<<dim3(64 + 64, B), 256, 0, stream>>>(adj, X, Wnf, Wnm, rowbits, base, P);
    v2B_kernel<<<dim3(N, B), 256, 0, stream>>>(base, P, rowbits, colbits, V2);
    s3_kernel<<<dim3(N, B), 256, 0, stream>>>(base, P, V2, rowbits, colbits, Wnm, V3);
    bigstep_kernel<<<dim3(N, B), 256, 0, stream>>>(base, P, V2, V3, rowbits, colbits, Wnm, aggp);
    encode_kernel<<<dim3(N, B), 256, 0, stream>>>(X, Unf, Unm, aggp, enc);
    final_kernel<<<OUTD, 256, 0, stream>>>(enc, lw, lb, out);
}

// Round 11
// 122.909 us; speedup vs baseline: 1.4946x; 1.0135x over previous
//
#include <hip/hip_runtime.h>
#include <hip/hip_bf16.h>
#include <math.h>

#define B 8
#define N 256
#define F 64
#define OUTD 256
typedef unsigned long long u64;
typedef __attribute__((ext_vector_type(8))) short bf16x8;
typedef __attribute__((ext_vector_type(4))) float f32x4;

// split x into hi+lo bf16 parts (truncation; residual <= 2^-16 |x|)
__device__ __forceinline__ void build_frag(const float* v8, bf16x8& h, bf16x8& l) {
#pragma unroll
    for (int j = 0; j < 8; ++j) {
        unsigned u = __float_as_uint(v8[j]);
        unsigned hb = u & 0xffff0000u;
        float r = v8[j] - __uint_as_float(hb);
        h[j] = (short)(hb >> 16);
        l[j] = (short)(__float_as_uint(r) >> 16);
    }
}

// ---------------------------------------------------------------------------
// A: fused pack_rows (bx<64) + prep (bx>=64). grid (64+64, B), 256 thr.
// ---------------------------------------------------------------------------
__global__ __launch_bounds__(256) void prepA_kernel(const int* __restrict__ adj,
                                                    const float* __restrict__ X,
                                                    const float* __restrict__ Wnf,
                                                    const float* __restrict__ Wnm,
                                                    u64* __restrict__ rowbits,
                                                    float* __restrict__ base,
                                                    float* __restrict__ P) {
    int b = blockIdx.y;
    int w = threadIdx.x >> 6;
    int lane = threadIdx.x & 63;
    if (blockIdx.x < 64) {
        int i = blockIdx.x * 4 + w;
#pragma unroll
        for (int wd = 0; wd < 4; ++wd) {
            int v = adj[(long)(b * N + i) * N + wd * 64 + lane];
            u64 bits = __ballot(v != 0);
            if (lane == 0) rowbits[(b * N + i) * 4 + wd] = bits;
        }
    } else {
        int n = (blockIdx.x - 64) * 4 + w;   // [0, 256)
        int bi = b * N + n;
        float x = X[(size_t)bi * F + lane];
        float acc = 0.f;
#pragma unroll
        for (int g = 0; g < F; ++g) acc = fmaf(Wnf[lane * F + g], __shfl(x, g, 64), acc);
        base[(size_t)bi * F + lane] = acc;
        float rs = fmaxf(acc, 0.f);
        float acc2 = 0.f;
#pragma unroll
        for (int g = 0; g < F; ++g) acc2 = fmaf(Wnm[lane * F + g], __shfl(rs, g, 64), acc2);
        P[(size_t)bi * F + lane] = acc2;
    }
}

// ---------------------------------------------------------------------------
// B: fused pack_cols + v2. grid (N, B), 256 thr.
// ---------------------------------------------------------------------------
__global__ __launch_bounds__(256) void v2B_kernel(const float* __restrict__ base,
                                                  const float* __restrict__ P,
                                                  const u64* __restrict__ rowbits,
                                                  u64* __restrict__ colbits,
                                                  float* __restrict__ V2) {
    int i = blockIdx.x, b = blockIdx.y;
    int t = threadIdx.x, w = t >> 6, f = t & 63;
    int bi = b * N + i;
    int bN = b * N;
    int iw = i >> 6, ib = i & 63;
    __shared__ float red[4][F];
    u64 rv = rowbits[(bN + w * 64 + f) * 4 + iw];
    u64 cw = __ballot((rv >> ib) & 1ull);
    if (f == 0) colbits[bi * 4 + w] = cw;
    u64 both = cw & rowbits[bi * 4 + w];
    const float* Pb = P + (size_t)bN * F;
    float acc = 0.f;
    for (int j = 0; j < 64; ++j) {
        float mk = ((both >> j) & 1ull) ? 1.f : 0.f;
        acc += mk * Pb[(w * 64 + j) * F + f];
    }
    red[w][f] = acc;
    __syncthreads();
    if (t < F) V2[(size_t)bi * F + t] = base[(size_t)bi * F + t] + red[0][t] + red[1][t] + red[2][t] + red[3][t];
}

// ---------------------------------------------------------------------------
// s3: V3[b,i] = base[b,i] + Wnm @ (sum_{k in both(i)} relu(V2[b,k]-P[b,i]))
// ---------------------------------------------------------------------------
__global__ __launch_bounds__(256) void s3_kernel(const float* __restrict__ base,
                                                 const float* __restrict__ P,
                                                 const float* __restrict__ V2g,
                                                 const u64* __restrict__ rowbits,
                                                 const u64* __restrict__ colbits,
                                                 const float* __restrict__ Wnm,
                                                 float* __restrict__ V3) {
    int i = blockIdx.x, b = blockIdx.y;
    int t = threadIdx.x, w = t >> 6, f = t & 63;
    int bi = b * N + i;
    __shared__ float red[4][F];
    u64 both = rowbits[bi * 4 + w] & colbits[bi * 4 + w];
    float pif = P[(size_t)bi * F + f];
    const float* Vb = V2g + (size_t)b * N * F;
    float acc = 0.f;
    for (int j = 0; j < 64; ++j) {
        float mk = ((both >> j) & 1ull) ? 1.f : 0.f;
        acc += mk * fmaxf(Vb[(w * 64 + j) * F + f] - pif, 0.f);
    }
    red[w][f] = acc;
    __syncthreads();
    float u = red[0][f] + red[1][f] + red[2][f] + red[3][f];
    __syncthreads();
    float wv[16];
    const float4* wr = (const float4*)(Wnm + (size_t)f * F + 16 * w);
#pragma unroll
    for (int q = 0; q < 4; ++q) *(float4*)&wv[q * 4] = wr[q];
    float a = 0.f;
#pragma unroll
    for (int q = 0; q < 16; ++q) a = fmaf(wv[q], __shfl(u, 16 * w + q, 64), a);
    red[w][f] = a;
    __syncthreads();
    if (t < F) V3[(size_t)bi * F + t] = base[(size_t)bi * F + t] + red[0][t] + red[1][t] + red[2][t] + red[3][t];
}

// ---------------------------------------------------------------------------
// bigstep via MFMA (hi/lo bf16 3-pass ~ fp32), per-kt LDS phasing.
// r11 change: Al fragments (low bf16 of Wnm) are wave-invariant -> staged in
// LDS (8 KB, written by wave 0, conflict-free lane-contiguous b128 reads at
// point of use). Frees ~32 VGPRs; __launch_bounds__(256,3) caps combined
// regs at 168 (no spill; need ~150) -> 3 waves/SIMD instead of 2.
// kt loop stays branch-free (r8/r9: data-dependent branches here are toxic).
// ---------------------------------------------------------------------------
__global__ __launch_bounds__(256, 3) void bigstep_kernel(
        const float* __restrict__ base,
        const float* __restrict__ P,
        const float* __restrict__ V2g,
        const float* __restrict__ V3,
        const u64* __restrict__ rowbits,
        const u64* __restrict__ colbits,
        const float* __restrict__ Wnm,
        float* __restrict__ agg) {
    int i = blockIdx.x, b = blockIdx.y;
    int t = threadIdx.x;
    int w = t >> 6, l = t & 63;
    int ln = l & 15, grp = l >> 4;
    int bi = b * N + i;
    int bN = b * N;
    __shared__ float m2lds[4][16][68];   // per-wave [k_local][g] f32, padded
    __shared__ bf16x8 alds[8][64];       // Al fragments (wave-invariant)
    __shared__ float red[4][F];
    __shared__ float v4buf[F];

    u64 rw = rowbits[bi * 4 + w];
    u64 cw = colbits[bi * 4 + w];
    u64 bothw = rw & cw;

    // A fragments: Wnm[m][g], m = 16ft+ln, g = 32ks+8grp+j  (hi in regs,
    // lo staged to LDS by wave 0 -- values depend only on lane, not wave)
    bf16x8 Ah[8];
#pragma unroll
    for (int ft = 0; ft < 4; ++ft) {
        const float4* wr = (const float4*)(Wnm + (size_t)(16 * ft + ln) * F);
#pragma unroll
        for (int ks = 0; ks < 2; ++ks) {
            float e[8];
            *(float4*)&e[0] = wr[8 * ks + 2 * grp];
            *(float4*)&e[4] = wr[8 * ks + 2 * grp + 1];
            bf16x8 h, lo;
            build_frag(e, h, lo);
            Ah[ft * 2 + ks] = h;
            if (w == 0) alds[ft * 2 + ks][l] = lo;
        }
    }
    // V2[i] at this lane's g positions
    float v2f[2][8];
    {
        const float4* vr = (const float4*)(V2g + (size_t)bi * F);
#pragma unroll
        for (int ks = 0; ks < 2; ++ks) {
            *(float4*)&v2f[ks][0] = vr[8 * ks + 2 * grp];
            *(float4*)&v2f[ks][4] = vr[8 * ks + 2 * grp + 1];
        }
    }
    __syncthreads();   // alds ready

    f32x4 acc2[4][4];   // [ft][kt] kept for agg
#pragma unroll
    for (int ft = 0; ft < 4; ++ft)
#pragma unroll
        for (int kt = 0; kt < 4; ++kt) acc2[ft][kt] = (f32x4){0.f, 0.f, 0.f, 0.f};

#pragma unroll
    for (int kt = 0; kt < 4; ++kt) {
        int kglob = w * 64 + kt * 16 + ln;
        // ---- GEMM1 (this kt) ----
        f32x4 acc1[4];
#pragma unroll
        for (int ft = 0; ft < 4; ++ft) acc1[ft] = (f32x4){0.f, 0.f, 0.f, 0.f};
        const float4* pr = (const float4*)(P + (size_t)(bN + kglob) * F);
#pragma unroll
        for (int ks = 0; ks < 2; ++ks) {
            float e[8];
            *(float4*)&e[0] = pr[8 * ks + 2 * grp];
            *(float4*)&e[4] = pr[8 * ks + 2 * grp + 1];
#pragma unroll
            for (int j = 0; j < 8; ++j) e[j] = fmaxf(v2f[ks][j] - e[j], 0.f);
            bf16x8 Bh, Bl;
            build_frag(e, Bh, Bl);
#pragma unroll
            for (int ft = 0; ft < 4; ++ft) {
                bf16x8 Alf = alds[ft * 2 + ks][l];
                acc1[ft] = __builtin_amdgcn_mfma_f32_16x16x32_bf16(Ah[ft * 2 + ks], Bh, acc1[ft], 0, 0, 0);
                acc1[ft] = __builtin_amdgcn_mfma_f32_16x16x32_bf16(Ah[ft * 2 + ks], Bl, acc1[ft], 0, 0, 0);
                acc1[ft] = __builtin_amdgcn_mfma_f32_16x16x32_bf16(Alf, Bh, acc1[ft], 0, 0, 0);
            }
        }
        // ---- M2 tile into LDS ----
        {
            float km = ((bothw >> (kt * 16 + ln)) & 1ull) ? 1.f : 0.f;
            const float* v3r = V3 + (size_t)(bN + kglob) * F;
#pragma unroll
            for (int ft = 0; ft < 4; ++ft) {
                int g0 = 16 * ft + 4 * grp;
                float4 v3v = *(const float4*)(v3r + g0);
                f32x4 tq = acc1[ft];
                float4 m2v;
                m2v.x = km * fmaxf(v3v.x - tq[0], 0.f);
                m2v.y = km * fmaxf(v3v.y - tq[1], 0.f);
                m2v.z = km * fmaxf(v3v.z - tq[2], 0.f);
                m2v.w = km * fmaxf(v3v.w - tq[3], 0.f);
                *(float4*)&m2lds[w][ln][g0] = m2v;
            }
        }
        // ---- GEMM2 (this kt) ----
#pragma unroll
        for (int ks = 0; ks < 2; ++ks) {
            int g0 = 32 * ks + 8 * grp;
            float e[8];
            *(float4*)&e[0] = *(const float4*)&m2lds[w][ln][g0];
            *(float4*)&e[4] = *(const float4*)&m2lds[w][ln][g0 + 4];
            bf16x8 Bh, Bl;
            build_frag(e, Bh, Bl);
#pragma unroll
            for (int ft = 0; ft < 4; ++ft) {
                bf16x8 Alf = alds[ft * 2 + ks][l];
                acc2[ft][kt] = __builtin_amdgcn_mfma_f32_16x16x32_bf16(Ah[ft * 2 + ks], Bh, acc2[ft][kt], 0, 0, 0);
                acc2[ft][kt] = __builtin_amdgcn_mfma_f32_16x16x32_bf16(Ah[ft * 2 + ks], Bl, acc2[ft][kt], 0, 0, 0);
                acc2[ft][kt] = __builtin_amdgcn_mfma_f32_16x16x32_bf16(Alf, Bh, acc2[ft][kt], 0, 0, 0);
            }
        }
    }

    // ---- S4 reduce ----
    float s4[4][4];
#pragma unroll
    for (int ft = 0; ft < 4; ++ft)
#pragma unroll
        for (int r = 0; r < 4; ++r)
            s4[ft][r] = acc2[ft][0][r] + acc2[ft][1][r] + acc2[ft][2][r] + acc2[ft][3][r];
#pragma unroll
    for (int m = 1; m <= 8; m <<= 1)
#pragma unroll
        for (int ft = 0; ft < 4; ++ft)
#pragma unroll
            for (int r = 0; r < 4; ++r)
                s4[ft][r] += __shfl_xor(s4[ft][r], m, 64);
    if (ln == 0) {
#pragma unroll
        for (int ft = 0; ft < 4; ++ft) {
            float4 q = make_float4(s4[ft][0], s4[ft][1], s4[ft][2], s4[ft][3]);
            *(float4*)&red[w][16 * ft + 4 * grp] = q;
        }
    }
    __syncthreads();
    if (t < F) v4buf[t] = base[(size_t)bi * F + t] + red[0][t] + red[1][t] + red[2][t] + red[3][t];
    __syncthreads();

    // ---- agg ----
    float v4r[4][4];
#pragma unroll
    for (int ft = 0; ft < 4; ++ft) {
        float4 q = *(const float4*)&v4buf[16 * ft + 4 * grp];
        v4r[ft][0] = q.x; v4r[ft][1] = q.y; v4r[ft][2] = q.z; v4r[ft][3] = q.w;
    }
    float av[4][4];
#pragma unroll
    for (int ft = 0; ft < 4; ++ft)
#pragma unroll
        for (int r = 0; r < 4; ++r) av[ft][r] = 0.f;
#pragma unroll
    for (int kt = 0; kt < 4; ++kt) {
        float rbm = ((rw >> (kt * 16 + ln)) & 1ull) ? 1.f : 0.f;
#pragma unroll
        for (int ft = 0; ft < 4; ++ft)
#pragma unroll
            for (int r = 0; r < 4; ++r)
                av[ft][r] += rbm * fmaxf(v4r[ft][r] - acc2[ft][kt][r], 0.f);
    }
#pragma unroll
    for (int m = 1; m <= 8; m <<= 1)
#pragma unroll
        for (int ft = 0; ft < 4; ++ft)
#pragma unroll
            for (int r = 0; r < 4; ++r)
                av[ft][r] += __shfl_xor(av[ft][r], m, 64);
    if (ln == 0) {
#pragma unroll
        for (int ft = 0; ft < 4; ++ft) {
            float4 q = make_float4(av[ft][0], av[ft][1], av[ft][2], av[ft][3]);
            *(float4*)&red[w][16 * ft + 4 * grp] = q;
        }
    }
    __syncthreads();
    if (t < F) agg[(size_t)bi * F + t] = red[0][t] + red[1][t] + red[2][t] + red[3][t];
}

// ---------------------------------------------------------------------------
// encode: enc = relu(Unf@X + Unm@agg); matvec tail split over 4 waves
// ---------------------------------------------------------------------------
__global__ __launch_bounds__(256) void encode_kernel(const float* __restrict__ X,
                                                     const float* __restrict__ Unf,
                                                     const float* __restrict__ Unm,
                                                     const float* __restrict__ agg,
                                                     float* __restrict__ enc) {
    int n = blockIdx.x, b = blockIdx.y;
    int t = threadIdx.x, w = t >> 6, f = t & 63;
    __shared__ float red[4][F];
    const float* urow = Unf + (size_t)n * N;
    const float* Xb = X + (size_t)b * N * F;
    float acc = 0.f;
    for (int j = 0; j < 64; ++j) {
        int m = w * 64 + j;
        acc += urow[m] * Xb[m * F + f];
    }
    red[w][f] = acc;
    __syncthreads();
    float msum = red[0][f] + red[1][f] + red[2][f] + red[3][f];
    __syncthreads();
    float ag = agg[((size_t)b * N + n) * F + f];
    float wv[16];
    const float4* wr = (const float4*)(Unm + (size_t)f * F + 16 * w);
#pragma unroll
    for (int q = 0; q < 4; ++q) *(float4*)&wv[q * 4] = wr[q];
    float a = 0.f;
#pragma unroll
    for (int q = 0; q < 16; ++q) a = fmaf(wv[q], __shfl(ag, 16 * w + q, 64), a);
    red[w][f] = a;
    __syncthreads();
    if (w == 0)
        enc[((size_t)b * N + n) * F + f] = fmaxf(msum + red[0][f] + red[1][f] + red[2][f] + red[3][f], 0.f);
}

// ---------------------------------------------------------------------------
// final: out[b,o] = sigmoid(enc_flat[b] . lw[o] + lb[o])   (float4 loads)
// ---------------------------------------------------------------------------
__global__ __launch_bounds__(256) void final_kernel(const float* __restrict__ enc,
                                                    const float* __restrict__ lw,
                                                    const float* __restrict__ lb,
                                                    float* __restrict__ out) {
    int o = blockIdx.x;
    int t = threadIdx.x;
    float acc[B];
#pragma unroll
    for (int b = 0; b < B; ++b) acc[b] = 0.f;
    const float4* lrow = (const float4*)(lw + (size_t)o * (N * F));
    const float4* e4 = (const float4*)enc;
    for (int k = t; k < (N * F) / 4; k += 256) {
        float4 wv = lrow[k];
#pragma unroll
        for (int b = 0; b < B; ++b) {
            float4 ev = e4[b * (N * F / 4) + k];
            acc[b] += wv.x * ev.x + wv.y * ev.y + wv.z * ev.z + wv.w * ev.w;
        }
    }
    __shared__ float red[B][256];
#pragma unroll
    for (int b = 0; b < B; ++b) red[b][t] = acc[b];
    __syncthreads();
    for (int off = 128; off > 0; off >>= 1) {
        if (t < off) {
#pragma unroll
            for (int b = 0; b < B; ++b) red[b][t] += red[b][t + off];
        }
        __syncthreads();
    }
    if (t < B) {
        float z = red[t][0] + lb[o];
        out[t * OUTD + o] = 1.f / (1.f + expf(-z));
    }
}

extern "C" void kernel_launch(void* const* d_in, const int* in_sizes, int n_in,
                              void* d_out, int out_size, void* d_ws, size_t ws_size,
                              hipStream_t stream) {
    const float* X   = (const float*)d_in[0];
    const int*   adj = (const int*)d_in[1];
    const float* Wnf = (const float*)d_in[2];
    const float* Wnm = (const float*)d_in[3];
    const float* Unf = (const float*)d_in[4];
    const float* Unm = (const float*)d_in[5];
    const float* lw  = (const float*)d_in[6];
    const float* lb  = (const float*)d_in[7];
    float* out = (float*)d_out;

    const long BNF = (long)B * N * F;
    u64* rowbits = (u64*)d_ws;
    u64* colbits = rowbits + (long)B * N * 4;
    float* fws = (float*)(colbits + (long)B * N * 4);
    float* base = fws;          fws += BNF;
    float* P    = fws;          fws += BNF;
    float* V2   = fws;          fws += BNF;
    float* V3   = fws;          fws += BNF;
    float* aggp = fws;          fws += BNF;
    float* enc  = fws;          fws += BNF;
    (void)ws_size; (void)in_sizes; (void)n_in; (void)out_size;

    prepA_kernel<<<dim3(64 + 64, B), 256, 0, stream>>>(adj, X, Wnf, Wnm, rowbits, base, P);
    v2B_kernel<<<dim3(N, B), 256, 0, stream>>>(base, P, rowbits, colbits, V2);
    s3_kernel<<<dim3(N, B), 256, 0, stream>>>(base, P, V2, rowbits, colbits, Wnm, V3);
    bigstep_kernel<<<dim3(N, B), 256, 0, stream>>>(base, P, V2, V3, rowbits, colbits, Wnm, aggp);
    encode_kernel<<<dim3(N, B), 256, 0, stream>>>(X, Unf, Unm, aggp, enc);
    final_kernel<<<OUTD, 256, 0, stream>>>(enc, lw, lb, out);
}